// Round 9
// baseline (404.641 us; speedup 1.0000x reference)
//
#include <hip/hip_runtime.h>

#define NT 128
#define SS 512
#define NB 16                          // batches per block
// workspace layout (floats) — identical to R8
#define WSF_P 0
#define WSF_M (256 * 128)
#define WSF_S (WSF_M + 256)
#define WSB_P (WSF_S + 256)
#define WSB_S (WSB_P + 256 * 128)

typedef float f32x4 __attribute__((ext_vector_type(4)));
typedef short bf16x8 __attribute__((ext_vector_type(8)));

__device__ __forceinline__ int fexp_of(float x) {
    return (int)((__float_as_uint(x) >> 23) & 0xFFu) - 127;
}
// barrier draining only LDS ops — global prefetches stay in flight
__device__ __forceinline__ void lds_barrier() {
    asm volatile("s_waitcnt lgkmcnt(0)\n\ts_barrier" ::: "memory");
}
__device__ __forceinline__ unsigned short bf16hi(float x) {
    return (unsigned short)(__float_as_uint(x) >> 16);   // truncation split
}
__device__ __forceinline__ float fromhi(unsigned short h) {
    return __uint_as_float((unsigned)h << 16);
}

__global__ void zero_out_kernel(float* out) { out[0] = 0.0f; }

// Batched-MFMA forward/backward CRF recursion.
// 32 blocks: 0..15 forward (alpha, t=1..255), 16..31 backward (q, t=510..255),
// each owning 16 batches. Per step: phase-1 = A(alpha 16x128, split bf16) x
// B(expT, split bf16) via 24 mfma_f32_16x16x32_bf16 (3 split terms, f32 acc);
// phase-2 = 256 threads rescale (per-batch anchor exponent), multiply exp(em),
// re-split to bf16 hi/lo LDS planes. K-slot ordering cancels between A and B;
// LDS planes XOR-granule swizzled (T2 pattern) for conflict-free A reads.
__global__ __launch_bounds__(256, 1) void crf_fb_mfma_kernel(
    const float* __restrict__ emissions,        // [B, S, NT] f32
    const int* __restrict__ tags,               // [B, S]
    const unsigned char* __restrict__ mask,     // [B, S]
    const float* __restrict__ trans,            // [NT, NT] f32
    float* __restrict__ out,                    // [1] f32
    float* __restrict__ ws)                     // workspace
{
    const bool fw  = (blockIdx.x < 16);
    const int  b0  = (blockIdx.x & 15) * NB;
    const int  tid = threadIdx.x;               // 0..255
    const int  l   = tid & 63;
    const int  w   = tid >> 6;                  // wave 0..3: out-states 32w..32w+31
    const int  m   = l & 15;                    // mfma "lane&15" index
    const int  g   = l >> 4;                    // mfma k-group
    const int  batch = tid >> 4;                // phase-2 batch 0..15
    const int  j8  = tid & 15;                  // phase-2 state-octet index

    __shared__ float          raw[NB * 132];        // matvec out, f32 (padded)
    __shared__ unsigned short hplane[NB * 144];     // alpha-hat hi bf16 (swizzled)
    __shared__ unsigned short lplane[NB * 144];     // alpha-hat lo bf16
    __shared__ float          red[NB * 16];         // small reductions

    const int bb = b0 + batch;
    const float* emRow = emissions + (size_t)bb * SS * NT;
    const int s0 = 8 * j8;

    // ---- gold score (forward blocks; off the recursion) ----
    if (fw) {
        const int* tg = tags + bb * SS;
        const unsigned char* mk = mask + bb * SS;
        float gold = 0.0f;
        for (int t = j8; t < SS; t += 16) {
            int tgv = tg[t];
            float mkv = mk[t] ? 1.0f : 0.0f;
            float a = emRow[(size_t)t * NT + tgv];
            if (t > 0) a += trans[tg[t - 1] * NT + tgv];
            gold += a * mkv;
        }
        red[tid] = gold;
    } else red[tid] = 0.0f;
    lds_barrier();
    if (fw && j8 == 0) {
        float gsum = 0.0f;
        #pragma unroll
        for (int i = 0; i < 16; i++) gsum += red[batch * 16 + i];
        atomicAdd(out, -gsum);
    }
    lds_barrier();

    // ---- static B fragments: exp(T) split hi/lo, fwd plain / bwd transposed ----
    // fwd: out[b][j] = sum_i alpha[b][i] eT[i][j]  -> B[k=i][n=j] = eT[i][j]
    // bwd: out[b][i] = sum_j eT[i][j] v[b][j]      -> B[k=j][n=i] = eT[i][j]
    bf16x8 Bh[2][4], Bl[2][4];
    #pragma unroll
    for (int tile = 0; tile < 2; tile++) {
        const int col = ((w << 1) + tile) * 16 + m;     // n-index
        #pragma unroll
        for (int c = 0; c < 4; c++) {
            #pragma unroll
            for (int e = 0; e < 8; e++) {
                const int kk = (c << 5) + (g << 3) + e; // k-index
                float tv = fw ? trans[(size_t)kk * NT + col]
                              : trans[(size_t)col * NT + kk];
                float ev = __expf(tv);
                unsigned short h = bf16hi(ev);
                Bh[tile][c][e] = (short)h;
                Bl[tile][c][e] = (short)bf16hi(ev - fromhi(h));
            }
        }
    }

    // ---- init alpha-hat (fwd: exp(em0 - M0); bwd: exp(em511)) ----
    const int t0 = fw ? 0 : (SS - 1);
    f32x4 e0a = *(const f32x4*)&emRow[(size_t)t0 * NT + s0];
    f32x4 e0b = *(const f32x4*)&emRow[(size_t)t0 * NT + s0 + 4];
    float M0 = 0.0f;
    if (fw) {
        float mm = fmaxf(fmaxf(fmaxf(e0a.x, e0a.y), fmaxf(e0a.z, e0a.w)),
                         fmaxf(fmaxf(e0b.x, e0b.y), fmaxf(e0b.z, e0b.w)));
        red[tid] = mm;
    } else red[tid] = 0.0f;
    lds_barrier();
    if (fw) {
        M0 = red[batch * 16];
        #pragma unroll
        for (int i = 1; i < 16; i++) M0 = fmaxf(M0, red[batch * 16 + i]);
    }
    {
        float yy[8];
        yy[0] = __expf(e0a.x - M0); yy[1] = __expf(e0a.y - M0);
        yy[2] = __expf(e0a.z - M0); yy[3] = __expf(e0a.w - M0);
        yy[4] = __expf(e0b.x - M0); yy[5] = __expf(e0b.y - M0);
        yy[6] = __expf(e0b.z - M0); yy[7] = __expf(e0b.w - M0);
        bf16x8 vh, vl;
        #pragma unroll
        for (int e = 0; e < 8; e++) {
            unsigned short h = bf16hi(yy[e]);
            vh[e] = (short)h;
            vl[e] = (short)bf16hi(yy[e] - fromhi(h));
        }
        const int wg = (j8 ^ (batch & 7)) << 3;         // swizzled granule
        *(bf16x8*)&hplane[batch * 144 + wg] = vh;
        *(bf16x8*)&lplane[batch * 144 + wg] = vl;
    }
    int Sacc = 0;

    // emission prefetch, 2 steps deep (vmcnt untouched by lds_barrier)
    f32x4 pA0, pA1, pB0, pB1;
    { int t1 = fw ? 1 : 510;
      pA0 = *(const f32x4*)&emRow[(size_t)t1 * NT + s0];
      pA1 = *(const f32x4*)&emRow[(size_t)t1 * NT + s0 + 4]; }
    { int t2 = fw ? 2 : 509;
      pB0 = *(const f32x4*)&emRow[(size_t)t2 * NT + s0];
      pB1 = *(const f32x4*)&emRow[(size_t)t2 * NT + s0 + 4]; }
    lds_barrier();

    // phase-1: read A frags (swizzled), 24 mfma (hh,lh,hl), write raw plane
    auto phase1 = [&]() {
        bf16x8 Ah[4], Al[4];
        #pragma unroll
        for (int c = 0; c < 4; c++) {
            const int gran = (((c << 2) + g) ^ (m & 7)) << 3;
            Ah[c] = *(const bf16x8*)&hplane[m * 144 + gran];
            Al[c] = *(const bf16x8*)&lplane[m * 144 + gran];
        }
        f32x4 a0 = {0.f, 0.f, 0.f, 0.f}, a1 = {0.f, 0.f, 0.f, 0.f};
        #pragma unroll
        for (int c = 0; c < 4; c++) {
            a0 = __builtin_amdgcn_mfma_f32_16x16x32_bf16(Ah[c], Bh[0][c], a0, 0, 0, 0);
            a1 = __builtin_amdgcn_mfma_f32_16x16x32_bf16(Ah[c], Bh[1][c], a1, 0, 0, 0);
            a0 = __builtin_amdgcn_mfma_f32_16x16x32_bf16(Al[c], Bh[0][c], a0, 0, 0, 0);
            a1 = __builtin_amdgcn_mfma_f32_16x16x32_bf16(Al[c], Bh[1][c], a1, 0, 0, 0);
            a0 = __builtin_amdgcn_mfma_f32_16x16x32_bf16(Ah[c], Bl[0][c], a0, 0, 0, 0);
            a1 = __builtin_amdgcn_mfma_f32_16x16x32_bf16(Ah[c], Bl[1][c], a1, 0, 0, 0);
        }
        // D: row(batch) = 4g+reg, col(state-in-tile) = m
        #pragma unroll
        for (int r = 0; r < 4; r++) {
            raw[((g << 2) + r) * 132 + (w << 5) + m]      = a0[r];
            raw[((g << 2) + r) * 132 + (w << 5) + 16 + m] = a1[r];
        }
    };

    // ---- recursion: 255 steps (bwd adds one final matvec after) ----
    #pragma unroll 1
    for (int i = 1; i <= 255; i++) {
        phase1();
        lds_barrier();
        // phase-2: rescale by per-batch anchor exponent, x exp(em_t), re-split
        f32x4 x0 = *(const f32x4*)&raw[batch * 132 + s0];
        f32x4 x1 = *(const f32x4*)&raw[batch * 132 + s0 + 4];
        float anchor = raw[batch * 132];
        int k = fexp_of(anchor);
        float scale = __uint_as_float((unsigned)(127 - k) << 23);   // 2^-k
        if (j8 == 0) Sacc += k;
        f32x4 ea = (i & 1) ? pA0 : pB0;
        f32x4 eb = (i & 1) ? pA1 : pB1;
        float yy[8];
        yy[0] = x0.x * scale * __expf(ea.x);
        yy[1] = x0.y * scale * __expf(ea.y);
        yy[2] = x0.z * scale * __expf(ea.z);
        yy[3] = x0.w * scale * __expf(ea.w);
        yy[4] = x1.x * scale * __expf(eb.x);
        yy[5] = x1.y * scale * __expf(eb.y);
        yy[6] = x1.z * scale * __expf(eb.z);
        yy[7] = x1.w * scale * __expf(eb.w);
        if (fw && i == 255) {                   // alpha_255 -> workspace
            float* wp = ws + WSF_P + (size_t)bb * NT + s0;
            f32x4 o0 = {yy[0], yy[1], yy[2], yy[3]};
            f32x4 o1 = {yy[4], yy[5], yy[6], yy[7]};
            *(f32x4*)wp = o0; *(f32x4*)(wp + 4) = o1;
        } else {
            bf16x8 vh, vl;
            #pragma unroll
            for (int e = 0; e < 8; e++) {
                unsigned short h = bf16hi(yy[e]);
                vh[e] = (short)h;
                vl[e] = (short)bf16hi(yy[e] - fromhi(h));
            }
            const int wg = (j8 ^ (batch & 7)) << 3;
            *(bf16x8*)&hplane[batch * 144 + wg] = vh;
            *(bf16x8*)&lplane[batch * 144 + wg] = vl;
        }
        if (i + 2 <= 255) {                     // refill prefetch slot
            int tn = fw ? (i + 2) : (511 - (i + 2));
            if (i & 1) { pA0 = *(const f32x4*)&emRow[(size_t)tn * NT + s0];
                         pA1 = *(const f32x4*)&emRow[(size_t)tn * NT + s0 + 4]; }
            else       { pB0 = *(const f32x4*)&emRow[(size_t)tn * NT + s0];
                         pB1 = *(const f32x4*)&emRow[(size_t)tn * NT + s0 + 4]; }
        }
        lds_barrier();
    }

    if (!fw) {                                  // final matvec: q_255, no emission
        phase1();
        lds_barrier();
        f32x4 x0 = *(const f32x4*)&raw[batch * 132 + s0];
        f32x4 x1 = *(const f32x4*)&raw[batch * 132 + s0 + 4];
        float anchor = raw[batch * 132];
        int k = fexp_of(anchor);
        float scale = __uint_as_float((unsigned)(127 - k) << 23);
        if (j8 == 0) Sacc += k;
        float* wp = ws + WSB_P + (size_t)bb * NT + s0;
        f32x4 o0 = {x0.x * scale, x0.y * scale, x0.z * scale, x0.w * scale};
        f32x4 o1 = {x1.x * scale, x1.y * scale, x1.z * scale, x1.w * scale};
        *(f32x4*)wp = o0; *(f32x4*)(wp + 4) = o1;
    }

    // ---- epilogue: per-batch scale bookkeeping ----
    if (j8 == 0) {
        if (fw) { ws[WSF_M + bb] = M0; ws[WSF_S + bb] = (float)Sacc; }
        else    { ws[WSB_S + bb] = (float)Sacc; }
    }
}

// partition_b = M0f + (Sf+Sb)*ln2 + log( sum_i alpha_hat[i] * q_hat[i] )
__global__ __launch_bounds__(64, 1) void crf_combine_kernel(
    const float* __restrict__ ws, float* __restrict__ out)
{
    const int b = blockIdx.x;
    const int l = threadIdx.x;                  // 0..63
    const float* pf = ws + WSF_P + b * NT;
    const float* pb = ws + WSB_P + b * NT;
    float d = pf[l] * pb[l] + pf[l + 64] * pb[l + 64];
    #pragma unroll
    for (int o = 32; o > 0; o >>= 1) d += __shfl_xor(d, o);
    if (l == 0) {
        float part = ws[WSF_M + b] +
                     (ws[WSF_S + b] + ws[WSB_S + b]) * 0.69314718055994531f +
                     __logf(d);
        atomicAdd(out, part);
    }
}

extern "C" void kernel_launch(void* const* d_in, const int* in_sizes, int n_in,
                              void* d_out, int out_size, void* d_ws, size_t ws_size,
                              hipStream_t stream) {
    const float*         emissions = (const float*)d_in[0];
    const int*           tags      = (const int*)d_in[1];
    const unsigned char* mask      = (const unsigned char*)d_in[2];
    const float*         trans     = (const float*)d_in[3];
    float*               out       = (float*)d_out;
    float*               ws        = (float*)d_ws;

    zero_out_kernel<<<1, 1, 0, stream>>>(out);
    crf_fb_mfma_kernel<<<32, 256, 0, stream>>>(emissions, tags, mask, trans, out, ws);
    crf_combine_kernel<<<256, 64, 0, stream>>>(ws, out);
}

// Round 10
// 194.906 us; speedup vs baseline: 2.0761x; 2.0761x over previous
//
#include <hip/hip_runtime.h>

#define NT 128
#define SS 512
#define MID 256
#define PW 132                         // padded per-wave column stride (floats)

// workspace layout (floats)
#define WSF_P 0                        // [256][128] forward alpha-hat at t=255
#define WSF_M (256 * 128)              // [256] M0f
#define WSF_S (WSF_M + 256)            // [256] Sf
#define WSB_P (WSF_S + 256)            // [256][128] backward q-hat at t=255
#define WSB_S (WSB_P + 256 * 128)      // [256] Sb

typedef float f32x2 __attribute__((ext_vector_type(2)));

__device__ __forceinline__ float rdlane(float v, int lane) {
    return __int_as_float(__builtin_amdgcn_readlane(__float_as_int(v), lane));
}
__device__ __forceinline__ int fexp_of(float x) {
    return (int)((__float_as_uint(x) >> 23) & 0xFFu) - 127;
}
// barrier draining only LDS ops — global prefetches stay in flight
__device__ __forceinline__ void lds_barrier() {
    asm volatile("s_waitcnt lgkmcnt(0)\n\ts_barrier" ::: "memory");
}

__global__ void zero_out_kernel(float* out) { out[0] = 0.0f; }

// Forward-backward split (R8) + three refinements:
//  - anchor-K rescale: K = exponent of state 0's alpha (tid 0), published via
//    the kslot piggyback -> deletes the 5-deep ds_swizzle reduce chain that
//    could overrun the adjacent matvec window every 4th step.
//  - gold score computed by BACKWARD blocks (fwd pays the M0 reduce) to
//    balance the two convoys' prologues.
//  - s_setprio(1) around the FMA loop (T5): the co-resident block in compute
//    phase preempts the one draining its barrier.
__global__ __launch_bounds__(256, 2) void crf_fb_kernel(
    const float* __restrict__ emissions,        // [B, S, NT] f32
    const int* __restrict__ tags,               // [B, S]
    const unsigned char* __restrict__ mask,     // [B, S]
    const float* __restrict__ trans,            // [NT, NT] f32
    float* __restrict__ out,                    // [1] f32
    float* __restrict__ ws)                     // workspace
{
    const bool fw  = (blockIdx.x < 256);
    const int b    = blockIdx.x & 255;
    const int tid  = threadIdx.x;               // 0..255
    const int l    = tid & 63;
    const int w    = tid >> 6;                  // wave 0..3: rows/states 32w..32w+31
    const int st   = (w << 5) + (l & 31);       // owned state (dup on lane halves)

    __shared__ float pbuf[2][4 * PW];           // [parity][wave*PW + col]
    __shared__ int   kslot;
    __shared__ float redf[4];
    __shared__ float redg[4];

    const float*         emB = emissions + (size_t)b * SS * NT;
    const int*           tgB = tags + b * SS;
    const unsigned char* mkB = mask + b * SS;

    // ---- gold score: BACKWARD blocks only (balances prologues) ----
    float gold = 0.0f;
    if (!fw) {
        for (int t = tid; t < SS; t += 256) {
            int tg   = tgB[t];
            float mk = mkB[t] ? 1.0f : 0.0f;
            float a  = emB[(size_t)t * NT + tg];
            if (t > 0) a += trans[tgB[t - 1] * NT + tg];
            gold += a * mk;
        }
    }

    // ---- expT: forward = row-block slice; backward = transposed slice ----
    f32x2 eTr[32];
    if (fw) {
        #pragma unroll
        for (int r = 0; r < 32; r++) {
            const float* row = trans + (size_t)((w << 5) + r) * NT;
            f32x2 v; v.x = __expf(row[l]); v.y = __expf(row[l + 64]);
            eTr[r] = v;
        }
    } else {
        #pragma unroll
        for (int r = 0; r < 32; r++) {          // eTr[r] = exp(T[{l,l+64}][32w+r])
            f32x2 v;
            v.x = __expf(trans[(size_t)l * NT + (w << 5) + r]);
            v.y = __expf(trans[(size_t)(l + 64) * NT + (w << 5) + r]);
            eTr[r] = v;
        }
    }

    // ---- init state + emission pipeline (4 deep, exp 2 steps off-chain) ----
    float p, M0 = 0.0f, S = 0.0f;
    int K = 0, kv_own = 0;
    float ex_o, ex_e, pd_o, pd_e;
    if (fw) {
        float a0 = emB[st];
        float v = a0;
        #pragma unroll
        for (int o = 16; o > 0; o >>= 1) v = fmaxf(v, __shfl_xor(v, o));
        if (l == 0) redf[w] = v;
        __syncthreads();
        M0 = fmaxf(fmaxf(redf[0], redf[1]), fmaxf(redf[2], redf[3]));
        p  = __expf(a0 - M0);
        ex_o = __expf(emB[(size_t)1 * NT + st]);
        ex_e = __expf(emB[(size_t)2 * NT + st]);
        pd_o = emB[(size_t)3 * NT + st];
        pd_e = emB[(size_t)4 * NT + st];
    } else {
        p = 1.0f;                               // q_511 = 1
        ex_o = __expf(emB[(size_t)511 * NT + st]);
        ex_e = __expf(emB[(size_t)510 * NT + st]);
        pd_o = emB[(size_t)509 * NT + st];
        pd_e = emB[(size_t)508 * NT + st];
    }

    // matvec over own 32 rows of the slice + 4-way combine; 1 lgkm barrier.
    // src is the broadcast vector (fwd: alpha; bwd: ex o q premultiplied).
    auto mv = [&](int q, bool kw, float src) -> float {
        f32x2 A0 = {0.f,0.f}, A1 = {0.f,0.f}, A2 = {0.f,0.f}, A3 = {0.f,0.f};
        __builtin_amdgcn_s_setprio(1);
        #pragma unroll
        for (int r = 0; r < 32; r += 4) {
            float q0 = rdlane(src, r + 0);
            float q1 = rdlane(src, r + 1);
            float q2 = rdlane(src, r + 2);
            float q3 = rdlane(src, r + 3);
            f32x2 b0 = {q0, q0}, b1 = {q1, q1}, b2 = {q2, q2}, b3 = {q3, q3};
            A0 = __builtin_elementwise_fma(b0, eTr[r + 0], A0);
            A1 = __builtin_elementwise_fma(b1, eTr[r + 1], A1);
            A2 = __builtin_elementwise_fma(b2, eTr[r + 2], A2);
            A3 = __builtin_elementwise_fma(b3, eTr[r + 3], A3);
        }
        __builtin_amdgcn_s_setprio(0);
        f32x2 s2 = (A0 + A1) + (A2 + A3);       // {partial col l, partial col l+64}
        pbuf[q][w * PW + l]      = s2.x;
        pbuf[q][w * PW + l + 64] = s2.y;
        if (kw && tid == 0) kslot = kv_own;     // anchor K rides the barrier
        lds_barrier();                          // lgkm-only: vmcnt untouched
        return (pbuf[q][0 * PW + st] + pbuf[q][1 * PW + st]) +
               (pbuf[q][2 * PW + st] + pbuf[q][3 * PW + st]);
    };
    auto rotF = [&](int t, float& pd, float& ex) {
        float nr = pd;
        int tn = t + 4; if (tn > SS - 1) tn = SS - 1;
        pd = emB[(size_t)tn * NT + st];
        ex = __expf(nr);
    };
    auto rotB = [&](int t, float& pd, float& ex) {
        float nr = pd;
        int tn = t - 3; if (tn < 0) tn = 0;
        pd = emB[(size_t)tn * NT + st];
        ex = __expf(nr);
    };

    // ---- recursion: groups of 4 steps; anchor rescale at sub-step 0 ----
    if (fw) {
        #pragma unroll 1
        for (int t = 1; t < MID; t += 4) {
            {   // sub 0 (parity 1): apply K, propose next kv (state-0 anchor)
                float sn = mv(1, false, p) * ex_o;
                p = ldexpf(sn, -K);
                S += (float)K;
                kv_own = fexp_of(p);            // only tid 0's value is consumed
                rotF(t, pd_o, ex_o);
            }
            if (t + 1 < MID) {   // sub 1 (parity 0): K anchor piggyback
                float sn = mv(0, true, p) * ex_e;
                K = kslot;                      // uniform read, off-chain
                p = sn;
                rotF(t + 1, pd_e, ex_e);
            }
            if (t + 2 < MID) { p = mv(1, false, p) * ex_o; rotF(t + 2, pd_o, ex_o); }
            if (t + 3 < MID) { p = mv(0, false, p) * ex_e; rotF(t + 3, pd_e, ex_e); }
        }
    } else {
        #pragma unroll 1
        for (int t = 510; t >= 258; t -= 4) {   // 64 full groups: q_510 .. q_255
            {   // sub 0 (parity 1)
                float sn = mv(1, false, p * ex_o);
                p = ldexpf(sn, -K);
                S += (float)K;
                kv_own = fexp_of(p);
                rotB(t, pd_o, ex_o);
            }
            {   // sub 1 (parity 0)
                float sn = mv(0, true, p * ex_e);
                K = kslot;
                p = sn;
                rotB(t - 1, pd_e, ex_e);
            }
            { p = mv(1, false, p * ex_o); rotB(t - 2, pd_o, ex_o); }
            { p = mv(0, false, p * ex_e); rotB(t - 3, pd_e, ex_e); }
        }
    }

    // ---- epilogue: publish vectors + scales; backward also reduces gold ----
    if (l < 32) {
        ws[(fw ? WSF_P : WSB_P) + b * NT + st] = p;
    }
    if (fw) {
        if (tid == 0) {
            ws[WSF_M + b] = M0;
            ws[WSF_S + b] = S;
        }
    } else {
        float g = gold;
        #pragma unroll
        for (int o = 32; o > 0; o >>= 1) g += __shfl_xor(g, o);
        if (l == 0) redg[w] = g;
        __syncthreads();
        if (tid == 0) {
            ws[WSB_S + b] = S;
            float gt = (redg[0] + redg[1]) + (redg[2] + redg[3]);
            atomicAdd(out, -gt);
        }
    }
}

// partition_b = M0f + (Sf+Sb)*ln2 + log( sum_i alpha_hat[i] * q_hat[i] )
__global__ __launch_bounds__(64, 1) void crf_combine_kernel(
    const float* __restrict__ ws, float* __restrict__ out)
{
    const int b = blockIdx.x;
    const int l = threadIdx.x;                  // 0..63
    const float* pf = ws + WSF_P + b * NT;
    const float* pb = ws + WSB_P + b * NT;
    float d = pf[l] * pb[l] + pf[l + 64] * pb[l + 64];
    #pragma unroll
    for (int o = 32; o > 0; o >>= 1) d += __shfl_xor(d, o);
    if (l == 0) {
        float part = ws[WSF_M + b] +
                     (ws[WSF_S + b] + ws[WSB_S + b]) * 0.69314718055994531f +
                     __logf(d);
        atomicAdd(out, part);
    }
}

extern "C" void kernel_launch(void* const* d_in, const int* in_sizes, int n_in,
                              void* d_out, int out_size, void* d_ws, size_t ws_size,
                              hipStream_t stream) {
    const float*         emissions = (const float*)d_in[0];
    const int*           tags      = (const int*)d_in[1];
    const unsigned char* mask      = (const unsigned char*)d_in[2];
    const float*         trans     = (const float*)d_in[3];
    float*               out       = (float*)d_out;
    float*               ws        = (float*)d_ws;

    zero_out_kernel<<<1, 1, 0, stream>>>(out);
    crf_fb_kernel<<<512, 256, 0, stream>>>(emissions, tags, mask, trans, out, ws);
    crf_combine_kernel<<<256, 64, 0, stream>>>(ws, out);
}